// Round 12
// baseline (430.633 us; speedup 1.0000x reference)
//
#include <hip/hip_runtime.h>
#include <hip/hip_bf16.h>

#define T_FRAMES 64

typedef __bf16 bf16x8 __attribute__((ext_vector_type(8)));
typedef __bf16 bf16x4 __attribute__((ext_vector_type(4)));
typedef float f32x4 __attribute__((ext_vector_type(4)));

// edge counts per level (fine->coarse): nnz = 3 * n_fine
#define NNZ0 15069
#define NNZ1 3768
#define NNZ2 942
#define NNZ3 237
#define N0 5023
#define N1 1256
#define N2 314
#define N3 79
#define N4 20

// All activation buffers are vt-major: [vert][t][C]. d_out stays [t][v][3].

// ---------------------------------------------------------------------------
// fused: blocks [0,640) = linear0 (latent -> vt-major bf16);
//        blocks [640,..) = weight fp32->bf16 (Wf zero-padded 3x288 -> 16x288)
// ---------------------------------------------------------------------------
__global__ __launch_bounds__(256) void prep_kernel(
    const float* __restrict__ latent, const float* __restrict__ W0,
    const float* __restrict__ b0, __bf16* __restrict__ out,
    const float* __restrict__ W1, const float* __restrict__ W2,
    const float* __restrict__ W3, const float* __restrict__ W4,
    const float* __restrict__ Wf, __bf16* __restrict__ o) {
  if (blockIdx.x < 640) {
    int id = blockIdx.x * 256 + threadIdx.x;
    int j = id % 2560;
    int t = id / 2560;
    const float* lrow = latent + t * 128;
    const float* wrow = W0 + j * 128;
    float acc = b0[j];
#pragma unroll 8
    for (int k = 0; k < 128; ++k) acc = fmaf(lrow[k], wrow[k], acc);
    out[((size_t)(j >> 7) * 64 + t) * 128 + (j & 127)] = (__bf16)acc;
    return;
  }
  int i = (blockIdx.x - 640) * 256 + threadIdx.x;
  if (i < 147456) { o[i] = (__bf16)W1[i]; return; }
  if (i < 221184) { o[i] = (__bf16)W2[i - 147456]; return; }
  if (i < 258048) { o[i] = (__bf16)W3[i - 221184]; return; }
  if (i < 276480) { o[i] = (__bf16)W4[i - 258048]; return; }
  if (i < 281088) {
    int j = i - 276480;
    o[i] = (j / 288 < 3) ? (__bf16)Wf[j] : (__bf16)0.f;
  }
}

// ---------------------------------------------------------------------------
// CSR build, single kernel: block b = level b; counts/scan/cursors in LDS
// (max n = 5023 -> 20.1 KB), packed records {col, val_bits} to global.
// ---------------------------------------------------------------------------
__global__ __launch_bounds__(256) void csr_build_kernel(
    const int* __restrict__ r0, const int* __restrict__ r1,
    const int* __restrict__ r2, const int* __restrict__ r3,
    const int* __restrict__ q0, const int* __restrict__ q1,
    const int* __restrict__ q2, const int* __restrict__ q3,
    const float* __restrict__ v0, const float* __restrict__ v1,
    const float* __restrict__ v2, const float* __restrict__ v3,
    int* __restrict__ o0, int* __restrict__ o1,
    int* __restrict__ o2, int* __restrict__ o3,
    int2* __restrict__ p0, int2* __restrict__ p1,
    int2* __restrict__ p2, int2* __restrict__ p3) {
  const int b = blockIdx.x;
  const int* rows = b == 0 ? r0 : b == 1 ? r1 : b == 2 ? r2 : r3;
  const int* cols = b == 0 ? q0 : b == 1 ? q1 : b == 2 ? q2 : q3;
  const float* vals = b == 0 ? v0 : b == 1 ? v1 : b == 2 ? v2 : v3;
  int* off = b == 0 ? o0 : b == 1 ? o1 : b == 2 ? o2 : o3;
  int2* pk = b == 0 ? p0 : b == 1 ? p1 : b == 2 ? p2 : p3;
  const int n = b == 0 ? N0 : b == 1 ? N1 : b == 2 ? N2 : N3;
  const int nnz = b == 0 ? NNZ0 : b == 1 ? NNZ1 : b == 2 ? NNZ2 : NNZ3;

  __shared__ int cnt[N0];
  __shared__ int part[256];

  for (int i = threadIdx.x; i < n; i += 256) cnt[i] = 0;
  __syncthreads();
  for (int e = threadIdx.x; e < nnz; e += 256) atomicAdd(&cnt[rows[e]], 1);
  __syncthreads();

  const int chunk = (n + 255) / 256;
  const int start = threadIdx.x * chunk;
  const int end = min(start + chunk, n);
  int s = 0;
  for (int i = start; i < end; ++i) s += cnt[i];
  part[threadIdx.x] = s;
  __syncthreads();
  for (int d = 1; d < 256; d <<= 1) {
    int v = (threadIdx.x >= d) ? part[threadIdx.x - d] : 0;
    __syncthreads();
    part[threadIdx.x] += v;
    __syncthreads();
  }
  int run = (threadIdx.x == 0) ? 0 : part[threadIdx.x - 1];
  for (int i = start; i < end; ++i) {
    int c = cnt[i];
    off[i] = run;
    cnt[i] = run;        // becomes cursor
    run += c;
  }
  if (threadIdx.x == 255) off[n] = run;
  __syncthreads();

  for (int e = threadIdx.x; e < nnz; e += 256) {
    int p = atomicAdd(&cnt[rows[e]], 1);
    pk[p] = make_int2(cols[e], __float_as_int(vals[e]));
  }
}

// ---------------------------------------------------------------------------
// CSR gather pool, vt-major, VECTORIZED: thread = (row, t, c-octet); each
// lane loads/stores bf16x8 (16B). Per edge a wave issues one dense ~1KB load
// (vs 16 x 128B scalar transactions before). Edge meta wave-uniform.
// ---------------------------------------------------------------------------
template <int C>
__global__ __launch_bounds__(256) void pool_csr_kernel(
    const __bf16* __restrict__ x, const int* __restrict__ off,
    const int2* __restrict__ pk, __bf16* __restrict__ out, int n_out) {
  constexpr int C8 = C / 8;
  unsigned id = blockIdx.x * 256u + threadIdx.x;
  unsigned total = (unsigned)n_out * T_FRAMES * C8;
  if (id >= total) return;
  const int c8 = id % C8;
  const int t = (id / C8) % T_FRAMES;
  const int row = id / (C8 * T_FRAMES);

  const int o0 = off[row], o1 = off[row + 1];
  float acc[8];
#pragma unroll
  for (int u = 0; u < 8; ++u) acc[u] = 0.f;

  for (int j = o0; j < o1; ++j) {
    const int2 rec = pk[j];
    const float val = __int_as_float(rec.y);
    const bf16x8 xv = *(const bf16x8*)(x + ((size_t)rec.x * T_FRAMES + t) * C + c8 * 8);
#pragma unroll
    for (int u = 0; u < 8; ++u) acc[u] = fmaf(val, (float)xv[u], acc[u]);
  }

  bf16x8 ov;
#pragma unroll
  for (int u = 0; u < 8; ++u) ov[u] = (__bf16)acc[u];
  *(bf16x8*)(out + ((size_t)row * T_FRAMES + t) * C + c8 * 8) = ov;
}

// ---------------------------------------------------------------------------
// spiral conv MFMA, vt-major (R7 form: MT m-tiles/wave, no fences).
// R6-R9 established: random-slab gather is fabric-BW-bound at ~1.9 TB/s;
// WV=2,MT=2 is the measured-best concurrency point (88us for conv0).
// ---------------------------------------------------------------------------
template <int CIN, int COUT, int WV, int MT>
__global__ __launch_bounds__(WV * 64) void conv_mfma_kernel(
    const __bf16* __restrict__ x, const int* __restrict__ idx,
    const __bf16* __restrict__ Wb, const float* __restrict__ bias,
    __bf16* __restrict__ out) {
  constexpr int K = 9 * CIN;
  constexpr int KK = K / 32;
  constexpr int NT = COUT / 16;

  const int lane = threadIdx.x & 63;
  const int wid = threadIdx.x >> 6;
  const int v = blockIdx.x;
  const int tq0 = (blockIdx.y * WV + wid) * MT;
  const int col = lane & 15;
  const int kg = lane >> 4;

  size_t vbase[9];
#pragma unroll
  for (int s = 0; s < 9; ++s)
    vbase[s] = (size_t)idx[v * 9 + s] * (T_FRAMES * CIN);

  bf16x8 a[MT][KK];
#pragma unroll
  for (int mt = 0; mt < MT; ++mt) {
    const size_t trow = (size_t)(tq0 + mt) * 16 + col;
#pragma unroll
    for (int kk = 0; kk < KK; ++kk) {
      const int s = (kk * 32) / CIN;
      const int ci0 = (kk * 32) % CIN;
      a[mt][kk] = *(const bf16x8*)(x + vbase[s] + trow * CIN + ci0 + kg * 8);
    }
  }

  f32x4 acc[MT][NT];
#pragma unroll
  for (int nt = 0; nt < NT; ++nt) {
    float b = bias[nt * 16 + col];
#pragma unroll
    for (int mt = 0; mt < MT; ++mt) acc[mt][nt] = (f32x4){b, b, b, b};
  }

#pragma unroll
  for (int kk = 0; kk < KK; ++kk) {
#pragma unroll
    for (int nt = 0; nt < NT; ++nt) {
      bf16x8 bfr = *(const bf16x8*)(Wb + (size_t)(nt * 16 + col) * K + kk * 32 + kg * 8);
#pragma unroll
      for (int mt = 0; mt < MT; ++mt)
        acc[mt][nt] = __builtin_amdgcn_mfma_f32_16x16x32_bf16(a[mt][kk], bfr, acc[mt][nt], 0, 0, 0);
    }
  }

#pragma unroll
  for (int mt = 0; mt < MT; ++mt) {
#pragma unroll
    for (int j = 0; j < 4; ++j) {
      const size_t tr = (size_t)(tq0 + mt) * 16 + kg * 4 + j;
#pragma unroll
      for (int nt = 0; nt < NT; ++nt) {
        float aa = acc[mt][nt][j];
        aa = aa > 0.f ? aa : expm1f(aa);
        out[((size_t)v * T_FRAMES + tr) * COUT + nt * 16 + col] = (__bf16)aa;
      }
    }
  }
}

// ---------------------------------------------------------------------------
// FINAL CONV stage A (dense): Z[u][s][t][c] = sum_ci z[u][t][ci]*Wf[c,s*32+ci]
// ---------------------------------------------------------------------------
__global__ __launch_bounds__(256) void final_dense_kernel(
    const __bf16* __restrict__ z, const __bf16* __restrict__ Wfp,
    __bf16* __restrict__ Z) {
  const int lane = threadIdx.x & 63;
  const int wid = threadIdx.x >> 6;
  const int u = blockIdx.x;
  const int col = lane & 15;
  const int kg = lane >> 4;
  const size_t trow = (size_t)wid * 16 + col;

  const bf16x8 a = *(const bf16x8*)(z + ((size_t)u * T_FRAMES + trow) * 32 + kg * 8);

#pragma unroll
  for (int s = 0; s < 9; ++s) {
    const bf16x8 w = *(const bf16x8*)(Wfp + col * 288 + s * 32 + kg * 8);
    f32x4 acc = (f32x4){0.f, 0.f, 0.f, 0.f};
    acc = __builtin_amdgcn_mfma_f32_16x16x32_bf16(a, w, acc, 0, 0, 0);
    if (col < 4) {
#pragma unroll
      for (int j = 0; j < 4; ++j) {
        const size_t tr = (size_t)wid * 16 + kg * 4 + j;
        Z[(((size_t)u * 9 + s) * T_FRAMES + tr) * 4 + col] = (__bf16)acc[j];
      }
    }
  }
}

// ---------------------------------------------------------------------------
// FINAL CONV stage B: out[t][v][c] = sum_s Z[idx[v,s]][s][t][c] + bf + actor
// ---------------------------------------------------------------------------
__global__ __launch_bounds__(256) void final_gather_kernel(
    const __bf16* __restrict__ Z, const int* __restrict__ idx,
    const float* __restrict__ bf3, const float* __restrict__ actor,
    float* __restrict__ out) {
  const unsigned id = blockIdx.x * 256u + threadIdx.x;
  if (id >= (unsigned)N0 * T_FRAMES) return;
  const int t = id & 63;
  const int v = id >> 6;

  float a0 = bf3[0], a1 = bf3[1], a2 = bf3[2];
#pragma unroll
  for (int s = 0; s < 9; ++s) {
    const int u = idx[v * 9 + s];
    const bf16x4 zz = *(const bf16x4*)(Z + (((size_t)u * 9 + s) * T_FRAMES + t) * 4);
    a0 += (float)zz[0];
    a1 += (float)zz[1];
    a2 += (float)zz[2];
  }
  float* op = out + ((size_t)t * N0 + v) * 3;
  op[0] = a0 + actor[v * 3 + 0];
  op[1] = a1 + actor[v * 3 + 1];
  op[2] = a2 + actor[v * 3 + 2];
}

// ---------------------------------------------------------------------------
extern "C" void kernel_launch(void* const* d_in, const int* in_sizes, int n_in_args,
                              void* d_out, int out_size, void* d_ws, size_t ws_size,
                              hipStream_t stream) {
  const float* latent = (const float*)d_in[0];
  const float* actor  = (const float*)d_in[1];
  const int* spiral0 = (const int*)d_in[2];
  const int* spiral1 = (const int*)d_in[3];
  const int* spiral2 = (const int*)d_in[4];
  const int* spiral3 = (const int*)d_in[5];
  const int* up0_rows = (const int*)d_in[6];
  const int* up0_cols = (const int*)d_in[7];
  const float* up0_vals = (const float*)d_in[8];
  const int* up1_rows = (const int*)d_in[9];
  const int* up1_cols = (const int*)d_in[10];
  const float* up1_vals = (const float*)d_in[11];
  const int* up2_rows = (const int*)d_in[12];
  const int* up2_cols = (const int*)d_in[13];
  const float* up2_vals = (const float*)d_in[14];
  const int* up3_rows = (const int*)d_in[15];
  const int* up3_cols = (const int*)d_in[16];
  const float* up3_vals = (const float*)d_in[17];
  const float* W0 = (const float*)d_in[18];
  const float* b0 = (const float*)d_in[19];
  const float* W1 = (const float*)d_in[20];
  const float* b1 = (const float*)d_in[21];
  const float* W2 = (const float*)d_in[22];
  const float* b2 = (const float*)d_in[23];
  const float* W3 = (const float*)d_in[24];
  const float* b3 = (const float*)d_in[25];
  const float* W4 = (const float*)d_in[26];
  const float* b4 = (const float*)d_in[27];
  const float* Wf = (const float*)d_in[28];
  const float* bf3 = (const float*)d_in[29];
  float* out = (float*)d_out;

  // ---- workspace layout (~62.5 MB) ----
  __bf16* poolbuf = (__bf16*)d_ws;              // 20,574,208 bf16 (41.1 MB)
  __bf16* convout = poolbuf + 20574208;         // 10,287,104 bf16 (20.6 MB)
  __bf16* wbuf = convout + 10287104;            // 281,088 bf16 (0.56 MB)
  __bf16* W1b = wbuf;                           // 128*1152
  __bf16* W2b = W1b + 147456;                   // 64*1152
  __bf16* W3b = W2b + 73728;                    // 64*576
  __bf16* W4b = W3b + 36864;                    // 32*576
  __bf16* Wfp = W4b + 18432;                    // 16*288 zero-padded
  int* csr = (int*)(wbuf + 281088);             // byte 62,284,800 (8B aligned)
  int* off0 = csr;            int* off1 = off0 + N0 + 1;
  int* off2 = off1 + N1 + 1;  int* off3 = off2 + N2 + 1;
  int2* pk0 = (int2*)(csr + 6676);              // 26,704 B in -> 8B aligned
  int2* pk1 = pk0 + NNZ0;
  int2* pk2 = pk1 + NNZ1;
  int2* pk3 = pk2 + NNZ2;
  // Z reuses poolbuf (dead after conv0 consumed it): 5023*9*64*4 bf16 = 23.1MB
  __bf16* Zbuf = poolbuf;

  // ---- CSR build (one kernel, 4 blocks, LDS count/scan/cursor) ----
  csr_build_kernel<<<4, 256, 0, stream>>>(
      up0_rows, up1_rows, up2_rows, up3_rows,
      up0_cols, up1_cols, up2_cols, up3_cols,
      up0_vals, up1_vals, up2_vals, up3_vals,
      off0, off1, off2, off3, pk0, pk1, pk2, pk3);

  // ---- fused weights->bf16 + dense latent->[20][64][128] ----
  prep_kernel<<<640 + (281088 + 255) / 256, 256, 0, stream>>>(
      latent, W0, b0, convout, W1, W2, W3, W4, Wf, wbuf);

  // ---- level 3: pool 20->79 (C=128), conv 128->128 ----
  pool_csr_kernel<128><<<(N3 * 64 * 16 + 255) / 256, 256, 0, stream>>>(
      convout, off3, pk3, poolbuf, N3);
  conv_mfma_kernel<128, 128, 1, 1><<<dim3(N3, 4), 64, 0, stream>>>(
      poolbuf, spiral3, W1b, b1, convout);

  // ---- level 2: pool 79->314 (C=128), conv 128->64 ----
  pool_csr_kernel<128><<<(N2 * 64 * 16 + 255) / 256, 256, 0, stream>>>(
      convout, off2, pk2, poolbuf, N2);
  conv_mfma_kernel<128, 64, 1, 1><<<dim3(N2, 4), 64, 0, stream>>>(
      poolbuf, spiral2, W2b, b2, convout);

  // ---- level 1: pool 314->1256 (C=64), conv 64->64 (WV=2,MT=2) ----
  pool_csr_kernel<64><<<(N1 * 64 * 8 + 255) / 256, 256, 0, stream>>>(
      convout, off1, pk1, poolbuf, N1);
  conv_mfma_kernel<64, 64, 2, 2><<<dim3(N1, 1), 128, 0, stream>>>(
      poolbuf, spiral1, W3b, b3, convout);

  // ---- level 0: pool 1256->5023 (C=64), conv 64->32 (WV=2,MT=2) ----
  pool_csr_kernel<64><<<(N0 * 64 * 8 + 255) / 256, 256, 0, stream>>>(
      convout, off0, pk0, poolbuf, N0);
  conv_mfma_kernel<64, 32, 2, 2><<<dim3(N0, 1), 128, 0, stream>>>(
      poolbuf, spiral0, W4b, b4, convout);

  // ---- final conv 32->3: dense Z transform, then once-each gather-sum ----
  final_dense_kernel<<<N0, 256, 0, stream>>>(convout, Wfp, Zbuf);
  final_gather_kernel<<<(N0 * T_FRAMES + 255) / 256, 256, 0, stream>>>(
      Zbuf, spiral0, bf3, actor, out);
}